// Round 10
// baseline (200.701 us; speedup 1.0000x reference)
//
#include <hip/hip_runtime.h>
#include <hip/hip_bf16.h>
#include <cstdint>
#include <cstddef>

#define T_ 8
#define N_ 16384
#define D_ 512
#define H_ 1024
#define O_ 64
#define IDX_COUNT (T_*N_)   // 131072

typedef __attribute__((ext_vector_type(4))) float f32x4;

#define WSCALE 64.0f        // weights pre-scaled into fp8 normal range
#define INV_WSCALE 0.015625f

// pack 8 floats -> 8 fp8 e4m3 (RNE, saturating) in one 64-bit value, byte e = elem e
__device__ __forceinline__ long long pack8fp8(f32x4 a, f32x4 b) {
  int lo = __builtin_amdgcn_cvt_pk_fp8_f32(a[0], a[1], 0, false);
  lo     = __builtin_amdgcn_cvt_pk_fp8_f32(a[2], a[3], lo, true);
  int hi = __builtin_amdgcn_cvt_pk_fp8_f32(b[0], b[1], 0, false);
  hi     = __builtin_amdgcn_cvt_pk_fp8_f32(b[2], b[3], hi, true);
  return (long long)(unsigned)lo | ((long long)hi << 32);
}

// ---------------- indices kernel: node_type is sorted repeat(arange(T)) -> indices == arange
__global__ void idx_kernel(float* __restrict__ out) {
  int i = blockIdx.x * 256 + threadIdx.x;
  out[i] = (float)i;
}

// ---------------- prep_w1: W1 f32 -> fp8 lane-linear A-fragment tiles ----------------
// Tile (t,hc,kk) = 8KB: chunk ch = (ks*4+hf)*64 + lane (8B); lane = g*16+r
//   chunk elem e = W1[t][d = kk*128+ks*32+g*8+e][h = hc*64+hf*16+r] * WSCALE
__global__ void prep_w1(const float* __restrict__ W1, char* __restrict__ ws) {
  int bid = blockIdx.x;            // t*64 + hc*4 + kk
  int kk = bid & 3, hc = (bid >> 2) & 15, t = bid >> 6;
  int tid = threadIdx.x;
  char* dst = ws + (size_t)bid * 8192;
  const float* src = W1 + ((size_t)t*D_ + kk*128)*H_ + hc*64;
#pragma unroll
  for (int i = 0; i < 4; i++) {
    int ch = i*256 + tid;          // 1024 8B chunks
    int lane = ch & 63, hf = (ch >> 6) & 3, ks = ch >> 8;
    int r = lane & 15, g = lane >> 4;
    f32x4 a, b;
#pragma unroll
    for (int e = 0; e < 4; e++) {
      a[e] = src[(size_t)(ks*32 + g*8 + e)*H_ + hf*16 + r] * WSCALE;
      b[e] = src[(size_t)(ks*32 + g*8 + 4 + e)*H_ + hf*16 + r] * WSCALE;
    }
    *(long long*)(dst + ch*8) = pack8fp8(a, b);
  }
}

// ---------------- prep_w2: W2 f32 -> fp8 A-frags, k scrambled to match in-lane H pack ----
// Chunk (t,hc) = 4KB: ch = (kb*4+of)*64 + lane (8B); elem e = m*4+j
//   value = W2[t][h = hc*64 + kb*32 + m*16 + g*4 + j][o = of*16 + r] * WSCALE
__global__ void prep_w2(const float* __restrict__ W2, char* __restrict__ ws) {
  int bid = blockIdx.x;            // t*16 + hc
  int hc = bid & 15, t = bid >> 4;
  int tid = threadIdx.x;
  char* dst = ws + (size_t)bid * 4096;
  const float* src = W2 + ((size_t)t*H_ + hc*64)*O_;
#pragma unroll
  for (int i = 0; i < 2; i++) {
    int ch = i*256 + tid;          // 512 8B chunks
    int lane = ch & 63, of = (ch >> 6) & 3, kb = ch >> 8;
    int r = lane & 15, g = lane >> 4;
    f32x4 a, b;
#pragma unroll
    for (int j = 0; j < 4; j++) {
      a[j] = src[(size_t)(kb*32 +      g*4 + j)*O_ + of*16 + r] * WSCALE;   // m=0
      b[j] = src[(size_t)(kb*32 + 16 + g*4 + j)*O_ + of*16 + r] * WSCALE;   // m=1
    }
    *(long long*)(dst + ch*8) = pack8fp8(a, b);
  }
}

// ---------------- fused GEMM1 -> sigmoid -> GEMM2 (swapped operands, fp8) ----------------
__device__ __forceinline__ void gl_lds16(const void* g, void* l) {
  __builtin_amdgcn_global_load_lds((const __attribute__((address_space(1))) unsigned int*)g,
                                   (__attribute__((address_space(3))) unsigned int*)l, 16, 0, 0);
}

// K=128 phases (64 total), 3-deep circular 8KB W1 buffers, stage depth 2.
// Per phase q: wait retires stage-group q-2 (leaving G(q-1) in flight), barrier,
// stage tile q+2 (2 gl_lds16, + w2 chunk on kk==0), 16 MFMAs on tile q.
// vmcnt(N) = size of G(q-1): 2/3/2/2 across kk (hc<15); hc=15: 2/2/2/0.
// (Counts verified in R8/R9; unchanged here.)
#define PHASE(HC, KK, NCNT, DO_W1, DO_W2) do {                                          \
  asm volatile("s_waitcnt vmcnt(" #NCNT ")" ::: "memory");                              \
  __builtin_amdgcn_s_barrier();                                                         \
  asm volatile("" ::: "memory");                                                        \
  if (DO_W1) {                                                                          \
    const int q2 = (HC)*4 + (KK) + 2;                                                   \
    int wr = rd + 2; if (wr >= 3) wr -= 3;                                              \
    const char* gsrc = w1base + (size_t)q2 * 8192;                                      \
    char* nb = &w1buf[0][0] + wr*8192;                                                  \
    gl_lds16(gsrc +        tid*16, nb +        w*1024);                                 \
    gl_lds16(gsrc + 4096 + tid*16, nb + 4096 + w*1024);                                 \
  }                                                                                     \
  if (DO_W2)                                                                            \
    gl_lds16(w2base + (size_t)((HC)+1)*4096 + tid*16, &w2buf[((HC)+1)&1][0] + w*1024);  \
  {                                                                                     \
    const char* cur = &w1buf[0][0] + rd*8192;                                           \
    __builtin_amdgcn_s_setprio(1);                                                      \
    _Pragma("unroll")                                                                   \
    for (int ks = 0; ks < 4; ks++) {                                                    \
      const int ki = (KK)*4 + ks;                                                       \
      _Pragma("unroll")                                                                 \
      for (int hf = 0; hf < 4; hf++) {                                                  \
        long long wf = *(const long long*)(cur + (((ks*4+hf)*64 + lane) << 3));         \
        hacc[hf] = __builtin_amdgcn_mfma_f32_16x16x32_fp8_fp8(wf, xf[ki], hacc[hf], 0,0,0); \
      }                                                                                 \
    }                                                                                   \
    __builtin_amdgcn_s_setprio(0);                                                      \
  }                                                                                     \
  rd = (rd == 2) ? 0 : rd + 1;                                                          \
} while (0)

// sigmoid computed IN PLACE in hacc; hb pack feeds GEMM2 B-frags directly
#define SIGMOID_GEMM2(HC) do {                                                          \
  _Pragma("unroll")                                                                     \
  for (int hf = 0; hf < 4; hf++) {                                                      \
    f32x4 bv = *(const f32x4*)(b1lds + (HC)*64 + hf*16 + g*4);                          \
    _Pragma("unroll")                                                                   \
    for (int j = 0; j < 4; j++) {                                                       \
      float v = hacc[hf][j] * INV_WSCALE + bv[j];                                       \
      hacc[hf][j] = 1.f / (1.f + __expf(-v));                                           \
    }                                                                                   \
  }                                                                                     \
  long long hb[2];                                                                      \
  hb[0] = pack8fp8(hacc[0], hacc[1]);                                                   \
  hb[1] = pack8fp8(hacc[2], hacc[3]);                                                   \
  const char* curw2 = &w2buf[(HC)&1][0];                                                \
  __builtin_amdgcn_s_setprio(1);                                                        \
  _Pragma("unroll")                                                                     \
  for (int kb = 0; kb < 2; kb++)                                                        \
    _Pragma("unroll")                                                                   \
    for (int of = 0; of < 4; of++) {                                                    \
      long long wf = *(const long long*)(curw2 + (((kb*4 + of)*64 + lane) << 3));       \
      oacc[of] = __builtin_amdgcn_mfma_f32_16x16x32_fp8_fp8(wf, hb[kb], oacc[of], 0,0,0); \
    }                                                                                   \
  __builtin_amdgcn_s_setprio(0);                                                        \
} while (0)

// 256 thr / 4 waves / 64 rows per block (16 rows per wave).
// Per-wave arch-VGPR demand: xf 32 + hacc 16 + oacc 16 + hb 4 + temps ~ 105 <= 128
// -> launch_bounds(256,4): 4 waves/SIMD, 4 blocks/CU (LDS 36KB x 4 = 144 <= 160KB),
// NO AGPR homing -> no v_accvgpr copies (R9: 212 unified regs/wave caused ~4-5K
// copies/wave = VALUBusy 37% > MfmaUtil 27%).
__global__ __launch_bounds__(256, 4) void gemm_fused(
    const float* __restrict__ x, const float* __restrict__ b1,
    const float* __restrict__ b2, const char* __restrict__ wsw1,
    const char* __restrict__ wsw2, float* __restrict__ out)
{
  __shared__ __align__(16) char w1buf[3][8192];    // 3-deep circular: 8KB W1 tiles (K=128)
  __shared__ __align__(16) char w2buf[2][4096];    // W2 chunk double buffer
  __shared__ __align__(16) float b1lds[1024];      // b1[t] (keeps loop VMEM-pure)

  const int tid = threadIdx.x;
  const int lane = tid & 63;
  const int w = tid >> 6;                  // wave 0..3, owns 16 rows
  // XCD swizzle: 2048 blocks -> one type per XCD (W1_t fp8 = 0.5MB stays L2-resident)
  const int bid = ((blockIdx.x & 7) << 8) | (blockIdx.x >> 3);
  const int t = bid >> 8;
  const int rblk = bid & 255;              // 256 row-blocks of 64 rows per type
  const int r = lane & 15;
  const int g = lane >> 4;

  const char* w1base = wsw1 + (size_t)t * (64*8192);   // 64 tiles of 8KB
  const char* w2base = wsw2 + (size_t)t * (16*4096);

  // prologue: stage tiles 0,1 + w2 chunk 0 + b1; x loads follow; syncthreads drains all
  gl_lds16(w1base +         tid*16, &w1buf[0][0] +        w*1024);
  gl_lds16(w1base +  4096 + tid*16, &w1buf[0][0] + 4096 + w*1024);
  gl_lds16(w1base +  8192 + tid*16, &w1buf[1][0] +        w*1024);
  gl_lds16(w1base + 12288 + tid*16, &w1buf[1][0] + 4096 + w*1024);
  gl_lds16(w2base + tid*16, &w2buf[0][0] + w*1024);
  gl_lds16((const char*)(b1 + (size_t)t*H_) + tid*16, (char*)b1lds + w*1024);

  // x rows -> persistent fp8 B-fragments, read exactly once, coalesced.
  // xf[ki]: lane holds x[n = rblk*64 + w*16 + r][d = ki*32 + g*8 + e]
  long long xf[16];
  {
    const float* xr = x + ((size_t)(t*N_ + rblk*64 + w*16 + r))*D_ + g*8;
#pragma unroll
    for (int ki = 0; ki < 16; ki++) {
      const f32x4* p = (const f32x4*)(xr + ki*32);
      xf[ki] = pack8fp8(p[0], p[1]);
    }
  }

  f32x4 oacc[4];   // O^T frags [of]: lane o = of*16+g*4+j, n = r
#pragma unroll
  for (int i = 0; i < 4; i++) oacc[i] = (f32x4){0.f,0.f,0.f,0.f};

  __syncthreads();   // full drain once: tiles 0,1 + w2c0 + b1 ready

  int rd = 0;        // circular buffer index of the tile being consumed

  for (int hc = 0; hc < 15; hc++) {
    f32x4 hacc[4];   // H^T frags [hf]: lane h = hf*16+g*4+j, n = r
#pragma unroll
    for (int i = 0; i < 4; i++) hacc[i] = (f32x4){0.f,0.f,0.f,0.f};

    PHASE(hc, 0, 2, true, true);    // retire G(q-2), stage tile q+2 + w2 hc+1
    PHASE(hc, 1, 3, true, false);   // G(q-1) carries the w2 -> vmcnt(3)
    PHASE(hc, 2, 2, true, false);
    PHASE(hc, 3, 2, true, false);
    SIGMOID_GEMM2(hc);
  }
  {
    // hc = 15 peeled: last stages at q=60 (tile 62) and q=61 (tile 63)
    f32x4 hacc[4];
#pragma unroll
    for (int i = 0; i < 4; i++) hacc[i] = (f32x4){0.f,0.f,0.f,0.f};

    PHASE(15, 0, 2, true,  false);
    PHASE(15, 1, 2, true,  false);
    PHASE(15, 2, 2, false, false);
    PHASE(15, 3, 0, false, false);
    SIGMOID_GEMM2(15);
  }

  // epilogue: direct f32x4 stores (un-scale W2), no LDS.
  const float* b2p = b2 + t*O_;
  float* obase = out + IDX_COUNT + ((size_t)(t*N_ + rblk*64 + w*16))*O_;
#pragma unroll
  for (int of = 0; of < 4; of++) {
    f32x4 bv = *(const f32x4*)(b2p + of*16 + g*4);
    f32x4 v;
#pragma unroll
    for (int j = 0; j < 4; j++) v[j] = oacc[of][j] * INV_WSCALE + bv[j];
    *(f32x4*)(obase + (size_t)r*O_ + of*16 + g*4) = v;
  }
}

// ---------------- naive f32 fallback (only if ws too small) ----------------
__global__ void naive_kernel(const float* __restrict__ x, const float* __restrict__ W1,
                             const float* __restrict__ b1, const float* __restrict__ W2,
                             const float* __restrict__ b2, float* __restrict__ out) {
  const int row = blockIdx.x;
  const int t = row >> 14;
  __shared__ float xs[512];
  __shared__ float hs[1024];
  const float* xr = x + (size_t)row * D_;
  for (int i = threadIdx.x; i < D_; i += 256) xs[i] = xr[i];
  __syncthreads();
  const float* w1t = W1 + (size_t)t * D_ * H_;
  for (int h = threadIdx.x; h < H_; h += 256) {
    float acc = b1[t*H_ + h];
    for (int k = 0; k < D_; k++) acc += xs[k] * w1t[(size_t)k*H_ + h];
    hs[h] = 1.f / (1.f + __expf(-acc));
  }
  __syncthreads();
  const float* w2t = W2 + (size_t)t * H_ * O_;
  for (int o = threadIdx.x; o < O_; o += 256) {
    float acc = b2[t*O_ + o];
    for (int k = 0; k < H_; k++) acc += hs[k] * w2t[k*O_ + o];
    out[IDX_COUNT + (size_t)row*O_ + o] = acc;
  }
}

extern "C" void kernel_launch(void* const* d_in, const int* in_sizes, int n_in,
                              void* d_out, int out_size, void* d_ws, size_t ws_size,
                              hipStream_t stream) {
  const float* x  = (const float*)d_in[0];
  const float* W1 = (const float*)d_in[1];
  const float* b1 = (const float*)d_in[2];
  const float* W2 = (const float*)d_in[3];
  const float* b2 = (const float*)d_in[4];
  float* out = (float*)d_out;

  idx_kernel<<<IDX_COUNT/256, 256, 0, stream>>>(out);

  const size_t w1_bytes = (size_t)T_*64*8192;    // 4,194,304
  const size_t w2_bytes = (size_t)T_*16*4096;    //   524,288
  if (ws_size >= w1_bytes + w2_bytes) {
    char* wsw1 = (char*)d_ws;
    char* wsw2 = wsw1 + w1_bytes;
    prep_w1<<<T_*64, 256, 0, stream>>>(W1, wsw1);
    prep_w2<<<T_*16, 256, 0, stream>>>(W2, wsw2);
    gemm_fused<<<T_*(N_/64), 256, 0, stream>>>(x, b1, b2, wsw1, wsw2, out);
  } else {
    naive_kernel<<<T_*N_, 256, 0, stream>>>(x, W1, b1, W2, b2, out);
  }
}

// Round 11
// 151.749 us; speedup vs baseline: 1.3226x; 1.3226x over previous
//
#include <hip/hip_runtime.h>
#include <hip/hip_bf16.h>
#include <cstdint>
#include <cstddef>

#define T_ 8
#define N_ 16384
#define D_ 512
#define H_ 1024
#define O_ 64
#define IDX_COUNT (T_*N_)   // 131072

typedef __attribute__((ext_vector_type(4))) float f32x4;
typedef __attribute__((ext_vector_type(4))) int   i32x4;
typedef __attribute__((ext_vector_type(8))) int   i32x8;

#define WSCALE 64.0f        // weights pre-scaled into fp8 normal range
#define INV_WSCALE 0.015625f
#define UNIT_SCALE 0x7f7f7f7f   // e8m0 exponent 127 -> x1.0 for every 32-elem block

// pack 4 floats -> 4 fp8 e4m3 bytes (RNE, saturating)
__device__ __forceinline__ int pack4fp8(f32x4 v) {
  int t = __builtin_amdgcn_cvt_pk_fp8_f32(v[0], v[1], 0, false);
  return  __builtin_amdgcn_cvt_pk_fp8_f32(v[2], v[3], t, true);
}
// pack 8 floats -> 8 fp8 bytes in one 64-bit value (GEMM2 path, verified R7)
__device__ __forceinline__ long long pack8fp8(f32x4 a, f32x4 b) {
  int lo = pack4fp8(a), hi = pack4fp8(b);
  return (long long)(unsigned)lo | ((long long)hi << 32);
}

// MX-scaled fp8 MFMA, K=128, unit scales (cbsz=0/blgp=0 -> both operands fp8 e4m3)
__device__ __forceinline__ f32x4 mfma128(i32x8 a, i32x8 b, f32x4 c) {
  return __builtin_amdgcn_mfma_scale_f32_16x16x128_f8f6f4(
      a, b, c, 0, 0, 0, UNIT_SCALE, 0, UNIT_SCALE);
}

// ---------------- indices kernel: node_type is sorted repeat(arange(T)) -> indices == arange
__global__ void idx_kernel(float* __restrict__ out) {
  int i = blockIdx.x * 256 + threadIdx.x;
  out[i] = (float)i;
}

// ---------------- prep_w1: W1 f32 -> fp8 K=128 A-fragment tiles ----------------
// Tile (t,hc,kk) = 8KB, layout [q(2)][hf(4)][lane(64)][16B], lane = g*16+r:
//   byte e' of chunk = W1[t][d = kk*128 + g*32 + q*16 + e'][h = hc*64 + hf*16 + r] * WSCALE
// Read in-kernel as two contiguous ds_read_b128 (lane-stride 16B: conflict-free).
__global__ void prep_w1(const float* __restrict__ W1, char* __restrict__ ws) {
  int bid = blockIdx.x;            // t*64 + hc*4 + kk
  int kk = bid & 3, hc = (bid >> 2) & 15, t = bid >> 6;
  int tid = threadIdx.x;
  char* dst = ws + (size_t)bid * 8192;
  const float* src = W1 + ((size_t)t*D_ + kk*128)*H_ + hc*64;
#pragma unroll
  for (int i = 0; i < 2; i++) {
    int ch = i*256 + tid;          // 512 16B chunks
    int lane = ch & 63, hf = (ch >> 6) & 3, q = ch >> 8;
    int r = lane & 15, g = lane >> 4;
    i32x4 pk;
#pragma unroll
    for (int e4 = 0; e4 < 4; e4++) {
      f32x4 v;
#pragma unroll
      for (int j = 0; j < 4; j++)
        v[j] = src[(size_t)(g*32 + q*16 + e4*4 + j)*H_ + hf*16 + r] * WSCALE;
      pk[e4] = pack4fp8(v);
    }
    *(i32x4*)(dst + q*4096 + ((hf*64 + lane) << 4)) = pk;
  }
}

// ---------------- prep_w2: W2 f32 -> fp8 A-frags, k scrambled to match in-lane H pack ----
// (verbatim from R7-R10, numerically verified)
__global__ void prep_w2(const float* __restrict__ W2, char* __restrict__ ws) {
  int bid = blockIdx.x;            // t*16 + hc
  int hc = bid & 15, t = bid >> 4;
  int tid = threadIdx.x;
  char* dst = ws + (size_t)bid * 4096;
  const float* src = W2 + ((size_t)t*H_ + hc*64)*O_;
#pragma unroll
  for (int i = 0; i < 2; i++) {
    int ch = i*256 + tid;          // 512 8B chunks
    int lane = ch & 63, of = (ch >> 6) & 3, kb = ch >> 8;
    int r = lane & 15, g = lane >> 4;
    f32x4 a, b;
#pragma unroll
    for (int j = 0; j < 4; j++) {
      a[j] = src[(size_t)(kb*32 +      g*4 + j)*O_ + of*16 + r] * WSCALE;   // m=0
      b[j] = src[(size_t)(kb*32 + 16 + g*4 + j)*O_ + of*16 + r] * WSCALE;   // m=1
    }
    *(long long*)(dst + ch*8) = pack8fp8(a, b);
  }
}

// ---------------- fused GEMM1 -> sigmoid -> GEMM2 ----------------
__device__ __forceinline__ void gl_lds16(const void* g, void* l) {
  __builtin_amdgcn_global_load_lds((const __attribute__((address_space(1))) unsigned int*)g,
                                   (__attribute__((address_space(3))) unsigned int*)l, 16, 0, 0);
}

// Counted-vmcnt schedule identical to R9/R10 (verified): K=128 tiles, 3-deep circular,
// stage depth 2, vmcnt 2/3/2/2 per hc (tail 2/2/2/0). Per phase now: 8 ds_read_b128 +
// 8 K=128 scale-MFMAs (4 hf x 2 nf) instead of 16 b64 + 16 K=32 MFMAs.
#define PHASE(HC, KK, NCNT, DO_W1, DO_W2) do {                                          \
  asm volatile("s_waitcnt vmcnt(" #NCNT ")" ::: "memory");                              \
  __builtin_amdgcn_s_barrier();                                                         \
  asm volatile("" ::: "memory");                                                        \
  if (DO_W1) {                                                                          \
    const int q2 = (HC)*4 + (KK) + 2;                                                   \
    int wr = rd + 2; if (wr >= 3) wr -= 3;                                              \
    const char* gsrc = w1base + (size_t)q2 * 8192;                                      \
    char* nb = &w1buf[0][0] + wr*8192;                                                  \
    gl_lds16(gsrc +        tid*16, nb +        w*1024);                                 \
    gl_lds16(gsrc + 4096 + tid*16, nb + 4096 + w*1024);                                 \
  }                                                                                     \
  if (DO_W2)                                                                            \
    gl_lds16(w2base + (size_t)((HC)+1)*4096 + tid*16, &w2buf[((HC)+1)&1][0] + w*1024);  \
  {                                                                                     \
    const char* cur = &w1buf[0][0] + rd*8192;                                           \
    __builtin_amdgcn_s_setprio(1);                                                      \
    _Pragma("unroll")                                                                   \
    for (int hf = 0; hf < 4; hf++) {                                                    \
      i32x4 lo = *(const i32x4*)(cur +        ((hf*64 + lane) << 4));                   \
      i32x4 hi = *(const i32x4*)(cur + 4096 + ((hf*64 + lane) << 4));                   \
      i32x8 a = __builtin_shufflevector(lo, hi, 0,1,2,3,4,5,6,7);                       \
      hacc[hf][0] = mfma128(a, xf[0][KK], hacc[hf][0]);                                 \
      hacc[hf][1] = mfma128(a, xf[1][KK], hacc[hf][1]);                                 \
    }                                                                                   \
    __builtin_amdgcn_s_setprio(0);                                                      \
  }                                                                                     \
  rd = (rd == 2) ? 0 : rd + 1;                                                          \
} while (0)

// sigmoid in place (rcpf: fp8 tolerance makes 1-ulp rcp free), then verified
// scrambled-k GEMM2 (16x16x32 fp8, unchanged from R7)
#define SIGMOID_GEMM2(HC) do {                                                          \
  _Pragma("unroll")                                                                     \
  for (int hf = 0; hf < 4; hf++) {                                                      \
    f32x4 bv = *(const f32x4*)(b1lds + (HC)*64 + hf*16 + g*4);                          \
    _Pragma("unroll")                                                                   \
    for (int nf = 0; nf < 2; nf++)                                                      \
      _Pragma("unroll")                                                                 \
      for (int j = 0; j < 4; j++) {                                                     \
        float v = hacc[hf][nf][j] * INV_WSCALE + bv[j];                                 \
        hacc[hf][nf][j] = __builtin_amdgcn_rcpf(1.f + __expf(-v));                      \
      }                                                                                 \
  }                                                                                     \
  long long hb[2][2];                                                                   \
  _Pragma("unroll")                                                                     \
  for (int kb = 0; kb < 2; kb++)                                                        \
    _Pragma("unroll")                                                                   \
    for (int nf = 0; nf < 2; nf++)                                                      \
      hb[kb][nf] = pack8fp8(hacc[2*kb][nf], hacc[2*kb+1][nf]);                          \
  const char* curw2 = &w2buf[(HC)&1][0];                                                \
  __builtin_amdgcn_s_setprio(1);                                                        \
  _Pragma("unroll")                                                                     \
  for (int kb = 0; kb < 2; kb++)                                                        \
    _Pragma("unroll")                                                                   \
    for (int of = 0; of < 4; of++) {                                                    \
      long long wf = *(const long long*)(curw2 + (((kb*4 + of)*64 + lane) << 3));       \
      oacc[of][0] = __builtin_amdgcn_mfma_f32_16x16x32_fp8_fp8(wf, hb[kb][0], oacc[of][0], 0,0,0); \
      oacc[of][1] = __builtin_amdgcn_mfma_f32_16x16x32_fp8_fp8(wf, hb[kb][1], oacc[of][1], 0,0,0); \
    }                                                                                   \
  __builtin_amdgcn_s_setprio(0);                                                        \
} while (0)

// 256 thr / 4 waves / 128 rows per block (32 rows per wave: W-frag reuse x2).
// Demand ~170 regs/wave <= 256 budget at (256,2).
__global__ __launch_bounds__(256, 2) void gemm_fused(
    const float* __restrict__ x, const float* __restrict__ b1,
    const float* __restrict__ b2, const char* __restrict__ wsw1,
    const char* __restrict__ wsw2, float* __restrict__ out)
{
  __shared__ __align__(16) char w1buf[3][8192];    // 3-deep circular: 8KB K=128 tiles
  __shared__ __align__(16) char w2buf[2][4096];    // W2 chunk double buffer
  __shared__ __align__(16) float b1lds[1024];      // b1[t] (keeps loop VMEM-pure)

  const int tid = threadIdx.x;
  const int lane = tid & 63;
  const int w = tid >> 6;                  // wave 0..3, owns 32 rows
  // XCD swizzle: 1024 blocks -> one type per XCD
  const int bid = ((blockIdx.x & 7) << 7) | (blockIdx.x >> 3);
  const int t = bid >> 7;
  const int rblk = bid & 127;              // 128 row-blocks of 128 rows per type
  const int r = lane & 15;
  const int g = lane >> 4;

  const char* w1base = wsw1 + (size_t)t * (64*8192);   // 64 tiles of 8KB
  const char* w2base = wsw2 + (size_t)t * (16*4096);

  // prologue: stage tiles 0,1 + w2 chunk 0 + b1; x loads follow; syncthreads drains all
  gl_lds16(w1base +         tid*16, &w1buf[0][0] +        w*1024);
  gl_lds16(w1base +  4096 + tid*16, &w1buf[0][0] + 4096 + w*1024);
  gl_lds16(w1base +  8192 + tid*16, &w1buf[1][0] +        w*1024);
  gl_lds16(w1base + 12288 + tid*16, &w1buf[1][0] + 4096 + w*1024);
  gl_lds16(w2base + tid*16, &w2buf[0][0] + w*1024);
  gl_lds16((const char*)(b1 + (size_t)t*H_) + tid*16, (char*)b1lds + w*1024);

  // x rows -> persistent fp8 K=128 B-fragments (i32x8), read exactly once.
  // xf[nf][kk]: lane holds x[n = rblk*128 + w*32 + nf*16 + r][k = kk*128 + g*32 + e], e=0..31
  i32x8 xf[2][4];
#pragma unroll
  for (int nf = 0; nf < 2; nf++) {
    const float* xr = x + ((size_t)(t*N_ + rblk*128 + w*32 + nf*16 + r))*D_ + g*32;
#pragma unroll
    for (int kk = 0; kk < 4; kk++) {
      const f32x4* p = (const f32x4*)(xr + kk*128);
      i32x8 a;
#pragma unroll
      for (int q = 0; q < 8; q++) a[q] = pack4fp8(p[q]);
      xf[nf][kk] = a;
    }
  }

  f32x4 oacc[4][2];   // O^T frags [of][nf]: lane o = of*16+g*4+j, n = nf*16+r
#pragma unroll
  for (int i = 0; i < 4; i++)
#pragma unroll
    for (int nf = 0; nf < 2; nf++) oacc[i][nf] = (f32x4){0.f,0.f,0.f,0.f};

  __syncthreads();   // full drain once: tiles 0,1 + w2c0 + b1 ready

  int rd = 0;        // circular buffer index of the tile being consumed

  for (int hc = 0; hc < 15; hc++) {
    f32x4 hacc[4][2];  // H^T frags [hf][nf]: lane h = hf*16+g*4+j, n = nf*16+r
#pragma unroll
    for (int i = 0; i < 4; i++)
#pragma unroll
      for (int nf = 0; nf < 2; nf++) hacc[i][nf] = (f32x4){0.f,0.f,0.f,0.f};

    PHASE(hc, 0, 2, true, true);    // retire G(q-2), stage tile q+2 + w2 hc+1
    PHASE(hc, 1, 3, true, false);   // G(q-1) carries the w2 -> vmcnt(3)
    PHASE(hc, 2, 2, true, false);
    PHASE(hc, 3, 2, true, false);
    SIGMOID_GEMM2(hc);
  }
  {
    // hc = 15 peeled: last stages at q=60 (tile 62) and q=61 (tile 63)
    f32x4 hacc[4][2];
#pragma unroll
    for (int i = 0; i < 4; i++)
#pragma unroll
      for (int nf = 0; nf < 2; nf++) hacc[i][nf] = (f32x4){0.f,0.f,0.f,0.f};

    PHASE(15, 0, 2, true,  false);
    PHASE(15, 1, 2, true,  false);
    PHASE(15, 2, 2, false, false);
    PHASE(15, 3, 0, false, false);
    SIGMOID_GEMM2(15);
  }

  // epilogue: direct f32x4 stores (un-scale W2), no LDS.
  const float* b2p = b2 + t*O_;
  float* obase = out + IDX_COUNT + ((size_t)(t*N_ + rblk*128 + w*32))*O_;
#pragma unroll
  for (int nf = 0; nf < 2; nf++)
#pragma unroll
    for (int of = 0; of < 4; of++) {
      f32x4 bv = *(const f32x4*)(b2p + of*16 + g*4);
      f32x4 v;
#pragma unroll
      for (int j = 0; j < 4; j++) v[j] = oacc[of][nf][j] * INV_WSCALE + bv[j];
      *(f32x4*)(obase + (size_t)(nf*16 + r)*O_ + of*16 + g*4) = v;
    }
}

// ---------------- naive f32 fallback (only if ws too small) ----------------
__global__ void naive_kernel(const float* __restrict__ x, const float* __restrict__ W1,
                             const float* __restrict__ b1, const float* __restrict__ W2,
                             const float* __restrict__ b2, float* __restrict__ out) {
  const int row = blockIdx.x;
  const int t = row >> 14;
  __shared__ float xs[512];
  __shared__ float hs[1024];
  const float* xr = x + (size_t)row * D_;
  for (int i = threadIdx.x; i < D_; i += 256) xs[i] = xr[i];
  __syncthreads();
  const float* w1t = W1 + (size_t)t * D_ * H_;
  for (int h = threadIdx.x; h < H_; h += 256) {
    float acc = b1[t*H_ + h];
    for (int k = 0; k < D_; k++) acc += xs[k] * w1t[(size_t)k*H_ + h];
    hs[h] = 1.f / (1.f + __expf(-acc));
  }
  __syncthreads();
  const float* w2t = W2 + (size_t)t * H_ * O_;
  for (int o = threadIdx.x; o < O_; o += 256) {
    float acc = b2[t*O_ + o];
    for (int k = 0; k < H_; k++) acc += hs[k] * w2t[k*O_ + o];
    out[IDX_COUNT + (size_t)row*O_ + o] = acc;
  }
}

extern "C" void kernel_launch(void* const* d_in, const int* in_sizes, int n_in,
                              void* d_out, int out_size, void* d_ws, size_t ws_size,
                              hipStream_t stream) {
  const float* x  = (const float*)d_in[0];
  const float* W1 = (const float*)d_in[1];
  const float* b1 = (const float*)d_in[2];
  const float* W2 = (const float*)d_in[3];
  const float* b2 = (const float*)d_in[4];
  float* out = (float*)d_out;

  idx_kernel<<<IDX_COUNT/256, 256, 0, stream>>>(out);

  const size_t w1_bytes = (size_t)T_*64*8192;    // 4,194,304
  const size_t w2_bytes = (size_t)T_*16*4096;    //   524,288
  if (ws_size >= w1_bytes + w2_bytes) {
    char* wsw1 = (char*)d_ws;
    char* wsw2 = wsw1 + w1_bytes;
    prep_w1<<<T_*64, 256, 0, stream>>>(W1, wsw1);
    prep_w2<<<T_*16, 256, 0, stream>>>(W2, wsw2);
    gemm_fused<<<T_*(N_/128), 256, 0, stream>>>(x, b1, b2, wsw1, wsw2, out);
  } else {
    naive_kernel<<<T_*N_, 256, 0, stream>>>(x, W1, b1, W2, b2, out);
  }
}